// Round 4
// baseline (739.016 us; speedup 1.0000x reference)
//
#include <hip/hip_runtime.h>
#include <hip/hip_bf16.h>

#define NODE_IN 128
#define EDGE_INF 128
#define HIDW 256
#define OUT_D 128
#define IN_DIM 512
#define EPSLN 1e-5f

using f32x4 = __attribute__((ext_vector_type(4))) float;
using bfv8  = __attribute__((ext_vector_type(8))) __bf16;

static __device__ __forceinline__ unsigned short f2bf(float f){
    union { float f; unsigned int u; } x; x.f = f;
    unsigned int r = x.u + 0x7fffu + ((x.u >> 16) & 1u);
    return (unsigned short)(r >> 16);
}

static __device__ __forceinline__ f32x4 mfma16(bfv8 a, bfv8 b, f32x4 c){
    return __builtin_amdgcn_mfma_f32_16x16x32_bf16(a, b, c, 0, 0, 0);
}

// ---------- weight convert: Wt[n][k] = bf16(W[k][n]) ----------
__global__ void k_wconv(const float* __restrict__ W, unsigned short* __restrict__ Wt, int K, int Nc){
    int idx = blockIdx.x*256 + threadIdx.x;
    if(idx >= K*Nc) return;
    int n = idx / K, k = idx - n*K;
    Wt[idx] = f2bf(W[(size_t)k*Nc + n]);
}

__global__ void k_count(const int* __restrict__ col, int* __restrict__ deg, int E){
    int e = blockIdx.x*256 + threadIdx.x;
    if(e < E) atomicAdd(&deg[col[e]], 1);
}

// ---------- hierarchical exclusive scan over deg[0..n) ----------
__global__ void k_scan1(const int* __restrict__ deg, int* __restrict__ bsum, int n){
    __shared__ int red[256];
    int b = blockIdx.x, t = threadIdx.x;
    int base = b*1024 + t*4;
    int v0=0,v1=0,v2=0,v3=0;
    if(base + 3 < n){ int4 q = *reinterpret_cast<const int4*>(deg+base); v0=q.x;v1=q.y;v2=q.z;v3=q.w; }
    else { if(base<n)v0=deg[base]; if(base+1<n)v1=deg[base+1]; if(base+2<n)v2=deg[base+2]; if(base+3<n)v3=deg[base+3]; }
    red[t] = v0+v1+v2+v3; __syncthreads();
    for(int off=128; off>0; off>>=1){ if(t<off) red[t]+=red[t+off]; __syncthreads(); }
    if(t==0) bsum[b] = red[0];
}

__global__ void k_scan2(int* __restrict__ bsum, int nb){
    __shared__ int sh[128];
    int t = threadIdx.x;
    int v = (t<nb)? bsum[t] : 0;
    sh[t]=v; __syncthreads();
    for(int off=1; off<128; off<<=1){
        int u = (t>=off)? sh[t-off] : 0;
        __syncthreads();
        sh[t] += u;
        __syncthreads();
    }
    if(t<nb) bsum[t] = sh[t]-v;   // exclusive
}

__global__ void k_scan3(const int* __restrict__ deg, const int* __restrict__ bsum,
                        int* __restrict__ indptr, int* __restrict__ cursor, int n){
    __shared__ int sh[256];
    int b = blockIdx.x, t = threadIdx.x;
    int base = b*1024 + t*4;
    int v[4] = {0,0,0,0};
    if(base + 3 < n){ int4 q = *reinterpret_cast<const int4*>(deg+base); v[0]=q.x;v[1]=q.y;v[2]=q.z;v[3]=q.w; }
    else { for(int j=0;j<4;j++) if(base+j<n) v[j]=deg[base+j]; }
    int s = v[0]+v[1]+v[2]+v[3];
    sh[t] = s; __syncthreads();
    for(int off=1; off<256; off<<=1){
        int u = (t>=off)? sh[t-off] : 0;
        __syncthreads();
        sh[t] += u;
        __syncthreads();
    }
    int p = bsum[b] + sh[t] - s;
    #pragma unroll
    for(int j=0;j<4;j++){
        int idx = base+j;
        if(idx < n){
            indptr[idx]=p; cursor[idx]=p;
            if(idx==n-1) indptr[n]=p+v[j];
            p += v[j];
        }
    }
}

__global__ void k_scatter(const int* __restrict__ col, int* __restrict__ cursor,
                          int* __restrict__ edge_of, int E){
    int e = blockIdx.x*256 + threadIdx.x;
    if(e < E){ int pos = atomicAdd(&cursor[col[e]], 1); edge_of[pos] = e; }
}

// ---------- gather: one wave per node; lane-halves cover 2 edges via float4 ----------
__global__ __launch_bounds__(256) void k_gather(
        const int* __restrict__ indptr, const int* __restrict__ edge_of,
        const float* __restrict__ eattr, const float* __restrict__ x,
        unsigned short* __restrict__ h0, int n){
    int node = blockIdx.x*4 + (threadIdx.x >> 6);
    if(node >= n) return;
    int l = threadIdx.x & 63;
    int half = l >> 5;            // 0: edges p, p+2, ... ; 1: edges p+1, p+3, ...
    int fi = (l & 31) * 4;        // 4 features per lane
    int s = indptr[node], e = indptr[node+1];
    float s0=0.f,s1=0.f,s2=0.f,s3=0.f;
    float m0=-INFINITY,m1=-INFINITY,m2=-INFINITY,m3=-INFINITY;
    int p = s + half;
    for(; p + 2 < e; p += 4){     // 2 edges per half in flight
        int e0 = edge_of[p], e1 = edge_of[p+2];
        float4 v0 = *reinterpret_cast<const float4*>(eattr + (size_t)e0*EDGE_INF + fi);
        float4 v1 = *reinterpret_cast<const float4*>(eattr + (size_t)e1*EDGE_INF + fi);
        s0 += v0.x + v1.x; s1 += v0.y + v1.y; s2 += v0.z + v1.z; s3 += v0.w + v1.w;
        m0 = fmaxf(m0, fmaxf(v0.x, v1.x)); m1 = fmaxf(m1, fmaxf(v0.y, v1.y));
        m2 = fmaxf(m2, fmaxf(v0.z, v1.z)); m3 = fmaxf(m3, fmaxf(v0.w, v1.w));
    }
    if(p < e){
        int e0 = edge_of[p];
        float4 v0 = *reinterpret_cast<const float4*>(eattr + (size_t)e0*EDGE_INF + fi);
        s0 += v0.x; s1 += v0.y; s2 += v0.z; s3 += v0.w;
        m0 = fmaxf(m0, v0.x); m1 = fmaxf(m1, v0.y); m2 = fmaxf(m2, v0.z); m3 = fmaxf(m3, v0.w);
    }
    // combine halves
    s0 += __shfl_xor(s0, 32); s1 += __shfl_xor(s1, 32);
    s2 += __shfl_xor(s2, 32); s3 += __shfl_xor(s3, 32);
    m0 = fmaxf(m0, __shfl_xor(m0, 32)); m1 = fmaxf(m1, __shfl_xor(m1, 32));
    m2 = fmaxf(m2, __shfl_xor(m2, 32)); m3 = fmaxf(m3, __shfl_xor(m3, 32));
    int d = e - s;
    float inv = 1.f / fmaxf((float)d, 1.f);
    if(d == 0){ m0=0.f; m1=0.f; m2=0.f; m3=0.f; }
    if(half == 0){
        float4 xv = *reinterpret_cast<const float4*>(x + (size_t)node*NODE_IN + fi);
        size_t r = (size_t)node * IN_DIM;
        ushort4 u;
        u.x=f2bf(s0); u.y=f2bf(s1); u.z=f2bf(s2); u.w=f2bf(s3);
        *reinterpret_cast<ushort4*>(h0 + r + fi) = u;
        u.x=f2bf(m0); u.y=f2bf(m1); u.z=f2bf(m2); u.w=f2bf(m3);
        *reinterpret_cast<ushort4*>(h0 + r + 128 + fi) = u;
        u.x=f2bf(s0*inv); u.y=f2bf(s1*inv); u.z=f2bf(s2*inv); u.w=f2bf(s3*inv);
        *reinterpret_cast<ushort4*>(h0 + r + 256 + fi) = u;
        u.x=f2bf(xv.x); u.y=f2bf(xv.y); u.z=f2bf(xv.z); u.w=f2bf(xv.w);
        *reinterpret_cast<ushort4*>(h0 + r + 384 + fi) = u;
    }
}

// ---------- fused MLP v2: 32 rows/wave, 128 rows/block, single-buffered wt ----------
template<int T>
static __device__ __forceinline__ void stage_w(const unsigned short* __restrict__ Wt, int K, int kt,
                                               unsigned short* dst, int w, int l){
    int lr = l & 15, lg = l >> 4;
    #pragma unroll
    for(int i=0;i<T/4;i++){
        int t = w*(T/4) + i;
        const unsigned short* src = Wt + (size_t)(t*16 + lr)*K + (size_t)kt*32 + lg*8;
        __builtin_amdgcn_global_load_lds(
            (const __attribute__((address_space(1))) void*)src,
            (__attribute__((address_space(3))) void*)(dst + (size_t)t*512),
            16, 0, 0);
    }
}

// LN + SiLU over one 16-row group; stores swizzled bf16 rows [rowoff..rowoff+16)
template<int NT>
static __device__ __forceinline__ void ln_silu_store(
    f32x4* acc, const float* __restrict__ bias,
    const float* __restrict__ g, const float* __restrict__ be,
    __bf16* __restrict__ hrow, int l, int rowoff)
{
    int lr = l & 15, lg = l >> 4;
    float s[4] = {0,0,0,0}, q[4] = {0,0,0,0};
    #pragma unroll
    for(int t=0;t<NT;t++){
        float b = bias[t*16 + lr];
        #pragma unroll
        for(int j=0;j<4;j++){
            float z = acc[t][j] + b;
            acc[t][j] = z;
            s[j] += z; q[j] += z*z;
        }
    }
    #pragma unroll
    for(int m=1;m<16;m<<=1){
        #pragma unroll
        for(int j=0;j<4;j++){
            s[j] += __shfl_xor(s[j], m, 64);
            q[j] += __shfl_xor(q[j], m, 64);
        }
    }
    float mean[4], inv[4];
    #pragma unroll
    for(int j=0;j<4;j++){
        mean[j] = s[j] * (1.f/256.f);
        float var = q[j] * (1.f/256.f) - mean[j]*mean[j];
        inv[j] = rsqrtf(var + EPSLN);
    }
    #pragma unroll
    for(int t=0;t<NT;t++){
        int colb = t*16 + lr;
        float gg = g[colb], bb = be[colb];
        #pragma unroll
        for(int j=0;j<4;j++){
            int row = rowoff + lg*4 + j;
            float y = (acc[t][j] - mean[j]) * inv[j] * gg + bb;
            float sil = y / (1.f + __expf(-y));
            int chunk = (colb >> 3) ^ (row & 7);
            hrow[row*256 + chunk*8 + (colb & 7)] = (__bf16)sil;
        }
    }
}

__global__ __launch_bounds__(256, 2) void k_mlp(
    const unsigned short* __restrict__ h0,
    const unsigned short* __restrict__ W0t, const float* __restrict__ b0, const float* __restrict__ g0, const float* __restrict__ be0,
    const unsigned short* __restrict__ W1t, const float* __restrict__ b1, const float* __restrict__ g1, const float* __restrict__ be1,
    const unsigned short* __restrict__ W2t, const float* __restrict__ b2, const float* __restrict__ g2, const float* __restrict__ be2,
    const unsigned short* __restrict__ W3t, const float* __restrict__ b3,
    float* __restrict__ out, int n)
{
    __shared__ __bf16 hb[4][32][256];            // 64 KB
    __shared__ unsigned short wt[16*512];        // 16 KB, single-buffered weight tile
    int w = threadIdx.x >> 6;
    int l = threadIdx.x & 63;
    int lr = l & 15, lg = l >> 4;
    int row0 = blockIdx.x*128 + w*32;
    __bf16* hrow = &hb[w][0][0];

    f32x4 acc[2][16];
    f32x4 zero = {0.f,0.f,0.f,0.f};

    // ---- L0: [32 x 512] @ [512 x 256], A from global h0 (depth-1 reg prefetch) ----
    #pragma unroll
    for(int t=0;t<16;t++){ acc[0][t] = zero; acc[1][t] = zero; }
    {
        const unsigned short* ap0 = h0 + (size_t)(row0 + lr)*IN_DIM + lg*8;
        bfv8 a0c = *reinterpret_cast<const bfv8*>(ap0);
        bfv8 a1c = *reinterpret_cast<const bfv8*>(ap0 + 16*IN_DIM);
        #pragma unroll
        for(int kt=0; kt<16; kt++){
            __syncthreads();                         // all waves done reading wt (kt-1)
            stage_w<16>(W0t, IN_DIM, kt, wt, w, l);
            bfv8 a0n = a0c, a1n = a1c;
            if(kt < 15){
                a0n = *reinterpret_cast<const bfv8*>(ap0 + (kt+1)*32);
                a1n = *reinterpret_cast<const bfv8*>(ap0 + 16*IN_DIM + (kt+1)*32);
            }
            __syncthreads();                         // wt staged (vmcnt0 drain)
            #pragma unroll
            for(int t=0;t<16;t++){
                bfv8 b = *reinterpret_cast<const bfv8*>(wt + t*512 + l*8);
                acc[0][t] = mfma16(a0c, b, acc[0][t]);
                acc[1][t] = mfma16(a1c, b, acc[1][t]);
            }
            a0c = a0n; a1c = a1n;
        }
    }
    ln_silu_store<16>(acc[0], b0, g0, be0, hrow, l, 0);
    ln_silu_store<16>(acc[1], b0, g0, be0, hrow, l, 16);

    // ---- L1 ----
    #pragma unroll
    for(int t=0;t<16;t++){ acc[0][t] = zero; acc[1][t] = zero; }
    #pragma unroll
    for(int kt=0; kt<8; kt++){
        __syncthreads();
        stage_w<16>(W1t, HIDW, kt, wt, w, l);
        __syncthreads();
        int chunk = (kt*4 + lg) ^ (lr & 7);
        bfv8 a0 = *reinterpret_cast<const bfv8*>(hrow + lr*256 + chunk*8);
        bfv8 a1 = *reinterpret_cast<const bfv8*>(hrow + (16+lr)*256 + chunk*8);
        #pragma unroll
        for(int t=0;t<16;t++){
            bfv8 b = *reinterpret_cast<const bfv8*>(wt + t*512 + l*8);
            acc[0][t] = mfma16(a0, b, acc[0][t]);
            acc[1][t] = mfma16(a1, b, acc[1][t]);
        }
    }
    ln_silu_store<16>(acc[0], b1, g1, be1, hrow, l, 0);
    ln_silu_store<16>(acc[1], b1, g1, be1, hrow, l, 16);

    // ---- L2 ----
    #pragma unroll
    for(int t=0;t<16;t++){ acc[0][t] = zero; acc[1][t] = zero; }
    #pragma unroll
    for(int kt=0; kt<8; kt++){
        __syncthreads();
        stage_w<16>(W2t, HIDW, kt, wt, w, l);
        __syncthreads();
        int chunk = (kt*4 + lg) ^ (lr & 7);
        bfv8 a0 = *reinterpret_cast<const bfv8*>(hrow + lr*256 + chunk*8);
        bfv8 a1 = *reinterpret_cast<const bfv8*>(hrow + (16+lr)*256 + chunk*8);
        #pragma unroll
        for(int t=0;t<16;t++){
            bfv8 b = *reinterpret_cast<const bfv8*>(wt + t*512 + l*8);
            acc[0][t] = mfma16(a0, b, acc[0][t]);
            acc[1][t] = mfma16(a1, b, acc[1][t]);
        }
    }
    ln_silu_store<16>(acc[0], b2, g2, be2, hrow, l, 0);
    ln_silu_store<16>(acc[1], b2, g2, be2, hrow, l, 16);

    // ---- L3: [32 x 256] @ [256 x 128] ----
    #pragma unroll
    for(int t=0;t<8;t++){ acc[0][t] = zero; acc[1][t] = zero; }
    #pragma unroll
    for(int kt=0; kt<8; kt++){
        __syncthreads();
        stage_w<8>(W3t, HIDW, kt, wt, w, l);
        __syncthreads();
        int chunk = (kt*4 + lg) ^ (lr & 7);
        bfv8 a0 = *reinterpret_cast<const bfv8*>(hrow + lr*256 + chunk*8);
        bfv8 a1 = *reinterpret_cast<const bfv8*>(hrow + (16+lr)*256 + chunk*8);
        #pragma unroll
        for(int t=0;t<8;t++){
            bfv8 b = *reinterpret_cast<const bfv8*>(wt + t*512 + l*8);
            acc[0][t] = mfma16(a0, b, acc[0][t]);
            acc[1][t] = mfma16(a1, b, acc[1][t]);
        }
    }
    #pragma unroll
    for(int t=0;t<8;t++){
        int col = t*16 + lr;
        float bb = b3[col];
        #pragma unroll
        for(int j=0;j<4;j++){
            #pragma unroll
            for(int gI=0;gI<2;gI++){
                int grow = row0 + gI*16 + lg*4 + j;
                if(grow < n) out[(size_t)grow*OUT_D + col] = acc[gI][t][j] + bb;
            }
        }
    }
}

extern "C" void kernel_launch(void* const* d_in, const int* in_sizes, int n_in,
                              void* d_out, int out_size, void* d_ws, size_t ws_size,
                              hipStream_t stream)
{
    const float* x          = (const float*)d_in[0];
    const int*   edge_index = (const int*)d_in[1];
    const float* edge_attr  = (const float*)d_in[2];
    const float* W0  = (const float*)d_in[5];
    const float* b0  = (const float*)d_in[6];
    const float* g0  = (const float*)d_in[7];
    const float* be0 = (const float*)d_in[8];
    const float* W1  = (const float*)d_in[9];
    const float* b1  = (const float*)d_in[10];
    const float* g1  = (const float*)d_in[11];
    const float* be1 = (const float*)d_in[12];
    const float* W2  = (const float*)d_in[13];
    const float* b2  = (const float*)d_in[14];
    const float* g2  = (const float*)d_in[15];
    const float* be2 = (const float*)d_in[16];
    const float* W3  = (const float*)d_in[17];
    const float* b3  = (const float*)d_in[18];

    int N = in_sizes[0] / NODE_IN;
    int E = in_sizes[2] / EDGE_INF;
    const int* col = edge_index + E;   // edge_index[1]

    char* p = (char*)d_ws;
    auto alloc = [&](size_t bytes) -> char* {
        char* r = p; p += (bytes + 255) & ~(size_t)255; return r;
    };
    int* deg     = (int*)alloc((size_t)N*4);
    int* indptr  = (int*)alloc((size_t)(N+1)*4);
    int* cursor  = (int*)alloc((size_t)N*4);
    int* edge_of = (int*)alloc((size_t)E*4);
    int nb = (N + 1023) / 1024;
    int* bsum    = (int*)alloc((size_t)nb*4);
    int Mpad = ((N + 127)/128)*128;
    unsigned short* h0  = (unsigned short*)alloc((size_t)Mpad*IN_DIM*2);
    unsigned short* W0t = (unsigned short*)alloc((size_t)IN_DIM*HIDW*2);
    unsigned short* W1t = (unsigned short*)alloc((size_t)HIDW*HIDW*2);
    unsigned short* W2t = (unsigned short*)alloc((size_t)HIDW*HIDW*2);
    unsigned short* W3t = (unsigned short*)alloc((size_t)HIDW*OUT_D*2);

    hipMemsetAsync(deg, 0, (size_t)N*4, stream);

    k_wconv<<<(IN_DIM*HIDW+255)/256, 256, 0, stream>>>(W0, W0t, IN_DIM, HIDW);
    k_wconv<<<(HIDW*HIDW+255)/256, 256, 0, stream>>>(W1, W1t, HIDW, HIDW);
    k_wconv<<<(HIDW*HIDW+255)/256, 256, 0, stream>>>(W2, W2t, HIDW, HIDW);
    k_wconv<<<(HIDW*OUT_D+255)/256, 256, 0, stream>>>(W3, W3t, HIDW, OUT_D);

    k_count<<<(E+255)/256, 256, 0, stream>>>(col, deg, E);
    k_scan1<<<nb, 256, 0, stream>>>(deg, bsum, N);
    k_scan2<<<1, 128, 0, stream>>>(bsum, nb);
    k_scan3<<<nb, 256, 0, stream>>>(deg, bsum, indptr, cursor, N);
    k_scatter<<<(E+255)/256, 256, 0, stream>>>(col, cursor, edge_of, E);
    k_gather<<<(N+3)/4, 256, 0, stream>>>(indptr, edge_of, edge_attr, x, h0, N);

    k_mlp<<<Mpad/128, 256, 0, stream>>>(h0,
        W0t, b0, g0, be0, W1t, b1, g1, be1, W2t, b2, g2, be2, W3t, b3,
        (float*)d_out, N);
}

// Round 5
// 649.268 us; speedup vs baseline: 1.1382x; 1.1382x over previous
//
#include <hip/hip_runtime.h>
#include <hip/hip_bf16.h>

#define NODE_IN 128
#define EDGE_INF 128
#define HIDW 256
#define OUT_D 128
#define IN_DIM 512
#define EPSLN 1e-5f

using f32x4 = __attribute__((ext_vector_type(4))) float;
using bfv8  = __attribute__((ext_vector_type(8))) __bf16;

static __device__ __forceinline__ unsigned short f2bf(float f){
    union { float f; unsigned int u; } x; x.f = f;
    unsigned int r = x.u + 0x7fffu + ((x.u >> 16) & 1u);
    return (unsigned short)(r >> 16);
}

static __device__ __forceinline__ f32x4 mfma16(bfv8 a, bfv8 b, f32x4 c){
    return __builtin_amdgcn_mfma_f32_16x16x32_bf16(a, b, c, 0, 0, 0);
}

// ---------- weight convert into LDS-fragment-tiled layout ----------
// chunk c = kt*NT + t holds 512 shorts: lane l (lr=l&15,lg=l>>4), elem e:
//   value = bf16( W[k][n] ), k = kt*32 + lg*8 + e, n = t*16 + lr
// so staging chunk c is one contiguous 1KB read per wave.
__global__ void k_wconv_tiled(const float* __restrict__ W, unsigned short* __restrict__ Wt,
                              int Nc, int NT, int total){
    int idx = blockIdx.x*256 + threadIdx.x;
    if(idx >= total) return;
    int e  = idx & 7;
    int l  = (idx >> 3) & 63;
    int c  = idx >> 9;
    int kt = c / NT, t = c - kt*NT;
    int lr = l & 15, lg = l >> 4;
    int k  = kt*32 + lg*8 + e;
    int n  = t*16 + lr;
    Wt[idx] = f2bf(W[(size_t)k*Nc + n]);
}

__global__ void k_count(const int* __restrict__ col, int* __restrict__ deg, int E){
    int e = blockIdx.x*256 + threadIdx.x;
    if(e < E) atomicAdd(&deg[col[e]], 1);
}

// ---------- hierarchical exclusive scan over deg[0..n) ----------
__global__ void k_scan1(const int* __restrict__ deg, int* __restrict__ bsum, int n){
    __shared__ int red[256];
    int b = blockIdx.x, t = threadIdx.x;
    int base = b*1024 + t*4;
    int v0=0,v1=0,v2=0,v3=0;
    if(base + 3 < n){ int4 q = *reinterpret_cast<const int4*>(deg+base); v0=q.x;v1=q.y;v2=q.z;v3=q.w; }
    else { if(base<n)v0=deg[base]; if(base+1<n)v1=deg[base+1]; if(base+2<n)v2=deg[base+2]; if(base+3<n)v3=deg[base+3]; }
    red[t] = v0+v1+v2+v3; __syncthreads();
    for(int off=128; off>0; off>>=1){ if(t<off) red[t]+=red[t+off]; __syncthreads(); }
    if(t==0) bsum[b] = red[0];
}

__global__ void k_scan2(int* __restrict__ bsum, int nb){
    __shared__ int sh[128];
    int t = threadIdx.x;
    int v = (t<nb)? bsum[t] : 0;
    sh[t]=v; __syncthreads();
    for(int off=1; off<128; off<<=1){
        int u = (t>=off)? sh[t-off] : 0;
        __syncthreads();
        sh[t] += u;
        __syncthreads();
    }
    if(t<nb) bsum[t] = sh[t]-v;   // exclusive
}

__global__ void k_scan3(const int* __restrict__ deg, const int* __restrict__ bsum,
                        int* __restrict__ indptr, int* __restrict__ cursor, int n){
    __shared__ int sh[256];
    int b = blockIdx.x, t = threadIdx.x;
    int base = b*1024 + t*4;
    int v[4] = {0,0,0,0};
    if(base + 3 < n){ int4 q = *reinterpret_cast<const int4*>(deg+base); v[0]=q.x;v[1]=q.y;v[2]=q.z;v[3]=q.w; }
    else { for(int j=0;j<4;j++) if(base+j<n) v[j]=deg[base+j]; }
    int s = v[0]+v[1]+v[2]+v[3];
    sh[t] = s; __syncthreads();
    for(int off=1; off<256; off<<=1){
        int u = (t>=off)? sh[t-off] : 0;
        __syncthreads();
        sh[t] += u;
        __syncthreads();
    }
    int p = bsum[b] + sh[t] - s;
    #pragma unroll
    for(int j=0;j<4;j++){
        int idx = base+j;
        if(idx < n){
            indptr[idx]=p; cursor[idx]=p;
            if(idx==n-1) indptr[n]=p+v[j];
            p += v[j];
        }
    }
}

__global__ void k_scatter(const int* __restrict__ col, int* __restrict__ cursor,
                          int* __restrict__ edge_of, int E){
    int e = blockIdx.x*256 + threadIdx.x;
    if(e < E){ int pos = atomicAdd(&cursor[col[e]], 1); edge_of[pos] = e; }
}

// ---------- gather: one wave per node; lane-halves cover 2 edges via float4 ----------
__global__ __launch_bounds__(256) void k_gather(
        const int* __restrict__ indptr, const int* __restrict__ edge_of,
        const float* __restrict__ eattr, const float* __restrict__ x,
        unsigned short* __restrict__ h0, int n){
    int node = blockIdx.x*4 + (threadIdx.x >> 6);
    if(node >= n) return;
    int l = threadIdx.x & 63;
    int half = l >> 5;            // 0: edges p, p+2, ... ; 1: edges p+1, p+3, ...
    int fi = (l & 31) * 4;        // 4 features per lane
    int s = indptr[node], e = indptr[node+1];
    float s0=0.f,s1=0.f,s2=0.f,s3=0.f;
    float m0=-INFINITY,m1=-INFINITY,m2=-INFINITY,m3=-INFINITY;
    int p = s + half;
    for(; p + 2 < e; p += 4){     // 2 edges per half in flight
        int e0 = edge_of[p], e1 = edge_of[p+2];
        float4 v0 = *reinterpret_cast<const float4*>(eattr + (size_t)e0*EDGE_INF + fi);
        float4 v1 = *reinterpret_cast<const float4*>(eattr + (size_t)e1*EDGE_INF + fi);
        s0 += v0.x + v1.x; s1 += v0.y + v1.y; s2 += v0.z + v1.z; s3 += v0.w + v1.w;
        m0 = fmaxf(m0, fmaxf(v0.x, v1.x)); m1 = fmaxf(m1, fmaxf(v0.y, v1.y));
        m2 = fmaxf(m2, fmaxf(v0.z, v1.z)); m3 = fmaxf(m3, fmaxf(v0.w, v1.w));
    }
    if(p < e){
        int e0 = edge_of[p];
        float4 v0 = *reinterpret_cast<const float4*>(eattr + (size_t)e0*EDGE_INF + fi);
        s0 += v0.x; s1 += v0.y; s2 += v0.z; s3 += v0.w;
        m0 = fmaxf(m0, v0.x); m1 = fmaxf(m1, v0.y); m2 = fmaxf(m2, v0.z); m3 = fmaxf(m3, v0.w);
    }
    // combine halves
    s0 += __shfl_xor(s0, 32); s1 += __shfl_xor(s1, 32);
    s2 += __shfl_xor(s2, 32); s3 += __shfl_xor(s3, 32);
    m0 = fmaxf(m0, __shfl_xor(m0, 32)); m1 = fmaxf(m1, __shfl_xor(m1, 32));
    m2 = fmaxf(m2, __shfl_xor(m2, 32)); m3 = fmaxf(m3, __shfl_xor(m3, 32));
    int d = e - s;
    float inv = 1.f / fmaxf((float)d, 1.f);
    if(d == 0){ m0=0.f; m1=0.f; m2=0.f; m3=0.f; }
    if(half == 0){
        float4 xv = *reinterpret_cast<const float4*>(x + (size_t)node*NODE_IN + fi);
        size_t r = (size_t)node * IN_DIM;
        ushort4 u;
        u.x=f2bf(s0); u.y=f2bf(s1); u.z=f2bf(s2); u.w=f2bf(s3);
        *reinterpret_cast<ushort4*>(h0 + r + fi) = u;
        u.x=f2bf(m0); u.y=f2bf(m1); u.z=f2bf(m2); u.w=f2bf(m3);
        *reinterpret_cast<ushort4*>(h0 + r + 128 + fi) = u;
        u.x=f2bf(s0*inv); u.y=f2bf(s1*inv); u.z=f2bf(s2*inv); u.w=f2bf(s3*inv);
        *reinterpret_cast<ushort4*>(h0 + r + 256 + fi) = u;
        u.x=f2bf(xv.x); u.y=f2bf(xv.y); u.z=f2bf(xv.z); u.w=f2bf(xv.w);
        *reinterpret_cast<ushort4*>(h0 + r + 384 + fi) = u;
    }
}

// ---------- fused MLP v4: tiled-weight staging (coalesced), 16 rows/wave, dbuf wt ----------
// stage chunk c = kt*NT + t: wave-contiguous 1KB from Wt_tiled
template<int NT>
static __device__ __forceinline__ void stage_w(const unsigned short* __restrict__ Wtil, int kt,
                                               unsigned short* dst, int w, int l){
    constexpr int TPW = NT/4;
    #pragma unroll
    for(int i=0;i<TPW;i++){
        int t = w*TPW + i;
        const unsigned short* src = Wtil + ((size_t)(kt*NT + t))*512 + l*8;
        __builtin_amdgcn_global_load_lds(
            (const __attribute__((address_space(1))) void*)src,
            (__attribute__((address_space(3))) void*)(dst + (size_t)t*512),
            16, 0, 0);
    }
}

template<int T>
static __device__ __forceinline__ void mfma_tiles(bfv8 a, const unsigned short* wb, f32x4* acc){
    #pragma unroll
    for(int t=0;t<T;t++){
        bfv8 b = *reinterpret_cast<const bfv8*>(wb + t*512);
        acc[t] = mfma16(a, b, acc[t]);
    }
}

template<int NT>
static __device__ __forceinline__ void ln_silu_store(
    f32x4* acc, const float* __restrict__ bias,
    const float* __restrict__ g, const float* __restrict__ be,
    __bf16* __restrict__ hrow, int l)
{
    int lr = l & 15, lg = l >> 4;
    float s[4] = {0,0,0,0}, q[4] = {0,0,0,0};
    #pragma unroll
    for(int t=0;t<NT;t++){
        float b = bias[t*16 + lr];
        #pragma unroll
        for(int j=0;j<4;j++){
            float z = acc[t][j] + b;
            acc[t][j] = z;
            s[j] += z; q[j] += z*z;
        }
    }
    #pragma unroll
    for(int m=1;m<16;m<<=1){
        #pragma unroll
        for(int j=0;j<4;j++){
            s[j] += __shfl_xor(s[j], m, 64);
            q[j] += __shfl_xor(q[j], m, 64);
        }
    }
    float mean[4], inv[4];
    #pragma unroll
    for(int j=0;j<4;j++){
        mean[j] = s[j] * (1.f/256.f);
        float var = q[j] * (1.f/256.f) - mean[j]*mean[j];
        inv[j] = rsqrtf(var + EPSLN);
    }
    #pragma unroll
    for(int t=0;t<NT;t++){
        int colb = t*16 + lr;
        float gg = g[colb], bb = be[colb];
        #pragma unroll
        for(int j=0;j<4;j++){
            int row = lg*4 + j;
            float y = (acc[t][j] - mean[j]) * inv[j] * gg + bb;
            float sil = y / (1.f + __expf(-y));
            int chunk = (colb >> 3) ^ (row & 7);
            hrow[row*256 + chunk*8 + (colb & 7)] = (__bf16)sil;
        }
    }
}

__global__ __launch_bounds__(256, 2) void k_mlp(
    const unsigned short* __restrict__ h0,
    const unsigned short* __restrict__ W0t, const float* __restrict__ b0, const float* __restrict__ g0, const float* __restrict__ be0,
    const unsigned short* __restrict__ W1t, const float* __restrict__ b1, const float* __restrict__ g1, const float* __restrict__ be1,
    const unsigned short* __restrict__ W2t, const float* __restrict__ b2, const float* __restrict__ g2, const float* __restrict__ be2,
    const unsigned short* __restrict__ W3t, const float* __restrict__ b3,
    float* __restrict__ out, int n)
{
    __shared__ __bf16 hb[4][16][256];            // 32 KB
    __shared__ unsigned short wt[2][16*512];     // 32 KB, double-buffered weight tile
    int w = threadIdx.x >> 6;
    int l = threadIdx.x & 63;
    int lr = l & 15, lg = l >> 4;
    int row0 = blockIdx.x*64 + w*16;
    __bf16* hrow = &hb[w][0][0];

    f32x4 acc[16];
    f32x4 zero = {0.f,0.f,0.f,0.f};

    // ---- L0: [16 x 512] @ [512 x 256]; all 16 A-frags preloaded to regs ----
    #pragma unroll
    for(int t=0;t<16;t++) acc[t] = zero;
    bfv8 a[16];
    {
        const unsigned short* ap = h0 + (size_t)(row0 + lr)*IN_DIM + lg*8;
        #pragma unroll
        for(int kt=0;kt<16;kt++) a[kt] = *reinterpret_cast<const bfv8*>(ap + kt*32);
    }
    stage_w<16>(W0t, 0, wt[0], w, l);
    __syncthreads();
    #pragma unroll
    for(int kt=0; kt<16; kt++){
        if(kt < 15) stage_w<16>(W0t, kt+1, wt[(kt+1)&1], w, l);
        mfma_tiles<16>(a[kt], wt[kt&1] + l*8, acc);
        __syncthreads();
    }
    ln_silu_store<16>(acc, b0, g0, be0, hrow, l);

    // ---- L1 ----
    #pragma unroll
    for(int t=0;t<16;t++) acc[t] = zero;
    stage_w<16>(W1t, 0, wt[0], w, l);
    __syncthreads();
    #pragma unroll
    for(int kt=0; kt<8; kt++){
        if(kt < 7) stage_w<16>(W1t, kt+1, wt[(kt+1)&1], w, l);
        int chunk = (kt*4 + lg) ^ (lr & 7);
        bfv8 av = *reinterpret_cast<const bfv8*>(hrow + lr*256 + chunk*8);
        mfma_tiles<16>(av, wt[kt&1] + l*8, acc);
        __syncthreads();
    }
    ln_silu_store<16>(acc, b1, g1, be1, hrow, l);

    // ---- L2 ----
    #pragma unroll
    for(int t=0;t<16;t++) acc[t] = zero;
    stage_w<16>(W2t, 0, wt[0], w, l);
    __syncthreads();
    #pragma unroll
    for(int kt=0; kt<8; kt++){
        if(kt < 7) stage_w<16>(W2t, kt+1, wt[(kt+1)&1], w, l);
        int chunk = (kt*4 + lg) ^ (lr & 7);
        bfv8 av = *reinterpret_cast<const bfv8*>(hrow + lr*256 + chunk*8);
        mfma_tiles<16>(av, wt[kt&1] + l*8, acc);
        __syncthreads();
    }
    ln_silu_store<16>(acc, b2, g2, be2, hrow, l);

    // ---- L3: [16 x 256] @ [256 x 128] ----
    #pragma unroll
    for(int t=0;t<8;t++) acc[t] = zero;
    stage_w<8>(W3t, 0, wt[0], w, l);
    __syncthreads();
    #pragma unroll
    for(int kt=0; kt<8; kt++){
        if(kt < 7) stage_w<8>(W3t, kt+1, wt[(kt+1)&1], w, l);
        int chunk = (kt*4 + lg) ^ (lr & 7);
        bfv8 av = *reinterpret_cast<const bfv8*>(hrow + lr*256 + chunk*8);
        mfma_tiles<8>(av, wt[kt&1] + l*8, acc);
        __syncthreads();
    }
    #pragma unroll
    for(int t=0;t<8;t++){
        int col = t*16 + lr;
        float bb = b3[col];
        #pragma unroll
        for(int j=0;j<4;j++){
            int grow = row0 + lg*4 + j;
            if(grow < n) out[(size_t)grow*OUT_D + col] = acc[t][j] + bb;
        }
    }
}

extern "C" void kernel_launch(void* const* d_in, const int* in_sizes, int n_in,
                              void* d_out, int out_size, void* d_ws, size_t ws_size,
                              hipStream_t stream)
{
    const float* x          = (const float*)d_in[0];
    const int*   edge_index = (const int*)d_in[1];
    const float* edge_attr  = (const float*)d_in[2];
    const float* W0  = (const float*)d_in[5];
    const float* b0  = (const float*)d_in[6];
    const float* g0  = (const float*)d_in[7];
    const float* be0 = (const float*)d_in[8];
    const float* W1  = (const float*)d_in[9];
    const float* b1  = (const float*)d_in[10];
    const float* g1  = (const float*)d_in[11];
    const float* be1 = (const float*)d_in[12];
    const float* W2  = (const float*)d_in[13];
    const float* b2  = (const float*)d_in[14];
    const float* g2  = (const float*)d_in[15];
    const float* be2 = (const float*)d_in[16];
    const float* W3  = (const float*)d_in[17];
    const float* b3  = (const float*)d_in[18];

    int N = in_sizes[0] / NODE_IN;
    int E = in_sizes[2] / EDGE_INF;
    const int* col = edge_index + E;   // edge_index[1]

    char* p = (char*)d_ws;
    auto alloc = [&](size_t bytes) -> char* {
        char* r = p; p += (bytes + 255) & ~(size_t)255; return r;
    };
    int* deg     = (int*)alloc((size_t)N*4);
    int* indptr  = (int*)alloc((size_t)(N+1)*4);
    int* cursor  = (int*)alloc((size_t)N*4);
    int* edge_of = (int*)alloc((size_t)E*4);
    int nb = (N + 1023) / 1024;
    int* bsum    = (int*)alloc((size_t)nb*4);
    int Mpad = ((N + 63)/64)*64;
    unsigned short* h0  = (unsigned short*)alloc((size_t)Mpad*IN_DIM*2);
    unsigned short* W0t = (unsigned short*)alloc((size_t)IN_DIM*HIDW*2);
    unsigned short* W1t = (unsigned short*)alloc((size_t)HIDW*HIDW*2);
    unsigned short* W2t = (unsigned short*)alloc((size_t)HIDW*HIDW*2);
    unsigned short* W3t = (unsigned short*)alloc((size_t)HIDW*OUT_D*2);

    hipMemsetAsync(deg, 0, (size_t)N*4, stream);

    // tiled weight images: NT = out_cols/16
    k_wconv_tiled<<<(IN_DIM*HIDW+255)/256, 256, 0, stream>>>(W0, W0t, HIDW, 16, IN_DIM*HIDW);
    k_wconv_tiled<<<(HIDW*HIDW+255)/256, 256, 0, stream>>>(W1, W1t, HIDW, 16, HIDW*HIDW);
    k_wconv_tiled<<<(HIDW*HIDW+255)/256, 256, 0, stream>>>(W2, W2t, HIDW, 16, HIDW*HIDW);
    k_wconv_tiled<<<(HIDW*OUT_D+255)/256, 256, 0, stream>>>(W3, W3t, OUT_D, 8, HIDW*OUT_D);

    k_count<<<(E+255)/256, 256, 0, stream>>>(col, deg, E);
    k_scan1<<<nb, 256, 0, stream>>>(deg, bsum, N);
    k_scan2<<<1, 128, 0, stream>>>(bsum, nb);
    k_scan3<<<nb, 256, 0, stream>>>(deg, bsum, indptr, cursor, N);
    k_scatter<<<(E+255)/256, 256, 0, stream>>>(col, cursor, edge_of, E);
    k_gather<<<(N+3)/4, 256, 0, stream>>>(indptr, edge_of, edge_attr, x, h0, N);

    k_mlp<<<Mpad/64, 256, 0, stream>>>(h0,
        W0t, b0, g0, be0, W1t, b1, g1, be1, W2t, b2, g2, be2, W3t, b3,
        (float*)d_out, N);
}

// Round 6
// 622.089 us; speedup vs baseline: 1.1880x; 1.0437x over previous
//
#include <hip/hip_runtime.h>
#include <hip/hip_bf16.h>

#define NODE_IN 128
#define EDGE_INF 128
#define HIDW 256
#define OUT_D 128
#define IN_DIM 512
#define EPSLN 1e-5f

using f32x4 = __attribute__((ext_vector_type(4))) float;
using bfv8  = __attribute__((ext_vector_type(8))) __bf16;

static __device__ __forceinline__ unsigned short f2bf(float f){
    union { float f; unsigned int u; } x; x.f = f;
    unsigned int r = x.u + 0x7fffu + ((x.u >> 16) & 1u);
    return (unsigned short)(r >> 16);
}

static __device__ __forceinline__ f32x4 mfma16(bfv8 a, bfv8 b, f32x4 c){
    return __builtin_amdgcn_mfma_f32_16x16x32_bf16(a, b, c, 0, 0, 0);
}

// ---------- weight convert into LDS-fragment-tiled layout (all 4 in one launch) ----------
// chunk c = kt*NT + t holds 512 shorts: lane l (lr=l&15,lg=l>>4), elem e:
//   value = bf16( W[k][n] ), k = kt*32 + lg*8 + e, n = t*16 + lr
__global__ void k_wconv_all(const float* __restrict__ W0, const float* __restrict__ W1,
                            const float* __restrict__ W2, const float* __restrict__ W3,
                            unsigned short* __restrict__ W0t, unsigned short* __restrict__ W1t,
                            unsigned short* __restrict__ W2t, unsigned short* __restrict__ W3t){
    int idx = blockIdx.x*256 + threadIdx.x;
    const float* W; unsigned short* Wt; int Nc, NT, off;
    if(idx < 131072){ W=W0; Wt=W0t; Nc=256; NT=16; off=idx; }
    else if(idx < 196608){ W=W1; Wt=W1t; Nc=256; NT=16; off=idx-131072; }
    else if(idx < 262144){ W=W2; Wt=W2t; Nc=256; NT=16; off=idx-196608; }
    else if(idx < 294912){ W=W3; Wt=W3t; Nc=128; NT=8;  off=idx-262144; }
    else return;
    int e  = off & 7;
    int l  = (off >> 3) & 63;
    int c  = off >> 9;
    int kt = c / NT, t = c - kt*NT;
    int lr = l & 15, lg = l >> 4;
    int k  = kt*32 + lg*8 + e;
    int n  = t*16 + lr;
    Wt[off] = f2bf(W[(size_t)k*Nc + n]);
}

__global__ void k_count(const int* __restrict__ col, int* __restrict__ deg, int E){
    int e = blockIdx.x*256 + threadIdx.x;
    if(e < E) atomicAdd(&deg[col[e]], 1);
}

// ---------- hierarchical exclusive scan over deg[0..n) ----------
__global__ void k_scan1(const int* __restrict__ deg, int* __restrict__ bsum, int n){
    __shared__ int red[256];
    int b = blockIdx.x, t = threadIdx.x;
    int base = b*1024 + t*4;
    int v0=0,v1=0,v2=0,v3=0;
    if(base + 3 < n){ int4 q = *reinterpret_cast<const int4*>(deg+base); v0=q.x;v1=q.y;v2=q.z;v3=q.w; }
    else { if(base<n)v0=deg[base]; if(base+1<n)v1=deg[base+1]; if(base+2<n)v2=deg[base+2]; if(base+3<n)v3=deg[base+3]; }
    red[t] = v0+v1+v2+v3; __syncthreads();
    for(int off=128; off>0; off>>=1){ if(t<off) red[t]+=red[t+off]; __syncthreads(); }
    if(t==0) bsum[b] = red[0];
}

__global__ void k_scan2(int* __restrict__ bsum, int nb){
    __shared__ int sh[128];
    int t = threadIdx.x;
    int v = (t<nb)? bsum[t] : 0;
    sh[t]=v; __syncthreads();
    for(int off=1; off<128; off<<=1){
        int u = (t>=off)? sh[t-off] : 0;
        __syncthreads();
        sh[t] += u;
        __syncthreads();
    }
    if(t<nb) bsum[t] = sh[t]-v;   // exclusive
}

__global__ void k_scan3(const int* __restrict__ deg, const int* __restrict__ bsum,
                        int* __restrict__ indptr, int* __restrict__ cursor, int n){
    __shared__ int sh[256];
    int b = blockIdx.x, t = threadIdx.x;
    int base = b*1024 + t*4;
    int v[4] = {0,0,0,0};
    if(base + 3 < n){ int4 q = *reinterpret_cast<const int4*>(deg+base); v[0]=q.x;v[1]=q.y;v[2]=q.z;v[3]=q.w; }
    else { for(int j=0;j<4;j++) if(base+j<n) v[j]=deg[base+j]; }
    int s = v[0]+v[1]+v[2]+v[3];
    sh[t] = s; __syncthreads();
    for(int off=1; off<256; off<<=1){
        int u = (t>=off)? sh[t-off] : 0;
        __syncthreads();
        sh[t] += u;
        __syncthreads();
    }
    int p = bsum[b] + sh[t] - s;
    #pragma unroll
    for(int j=0;j<4;j++){
        int idx = base+j;
        if(idx < n){
            indptr[idx]=p; cursor[idx]=p;
            if(idx==n-1) indptr[n]=p+v[j];
            p += v[j];
        }
    }
}

__global__ void k_scatter(const int* __restrict__ col, int* __restrict__ cursor,
                          int* __restrict__ edge_of, int E){
    int e = blockIdx.x*256 + threadIdx.x;
    if(e < E){ int pos = atomicAdd(&cursor[col[e]], 1); edge_of[pos] = e; }
}

// ---------- gather: one wave per node; lane-halves cover 2 edges via float4 ----------
__global__ __launch_bounds__(256) void k_gather(
        const int* __restrict__ indptr, const int* __restrict__ edge_of,
        const float* __restrict__ eattr, const float* __restrict__ x,
        unsigned short* __restrict__ h0, int n){
    int node = blockIdx.x*4 + (threadIdx.x >> 6);
    if(node >= n) return;
    int l = threadIdx.x & 63;
    int half = l >> 5;            // 0: edges p, p+2, ... ; 1: edges p+1, p+3, ...
    int fi = (l & 31) * 4;        // 4 features per lane
    int s = indptr[node], e = indptr[node+1];
    float s0=0.f,s1=0.f,s2=0.f,s3=0.f;
    float m0=-INFINITY,m1=-INFINITY,m2=-INFINITY,m3=-INFINITY;
    int p = s + half;
    for(; p + 2 < e; p += 4){     // 2 edges per half in flight
        int e0 = edge_of[p], e1 = edge_of[p+2];
        float4 v0 = *reinterpret_cast<const float4*>(eattr + (size_t)e0*EDGE_INF + fi);
        float4 v1 = *reinterpret_cast<const float4*>(eattr + (size_t)e1*EDGE_INF + fi);
        s0 += v0.x + v1.x; s1 += v0.y + v1.y; s2 += v0.z + v1.z; s3 += v0.w + v1.w;
        m0 = fmaxf(m0, fmaxf(v0.x, v1.x)); m1 = fmaxf(m1, fmaxf(v0.y, v1.y));
        m2 = fmaxf(m2, fmaxf(v0.z, v1.z)); m3 = fmaxf(m3, fmaxf(v0.w, v1.w));
    }
    if(p < e){
        int e0 = edge_of[p];
        float4 v0 = *reinterpret_cast<const float4*>(eattr + (size_t)e0*EDGE_INF + fi);
        s0 += v0.x; s1 += v0.y; s2 += v0.z; s3 += v0.w;
        m0 = fmaxf(m0, v0.x); m1 = fmaxf(m1, v0.y); m2 = fmaxf(m2, v0.z); m3 = fmaxf(m3, v0.w);
    }
    // combine halves
    s0 += __shfl_xor(s0, 32); s1 += __shfl_xor(s1, 32);
    s2 += __shfl_xor(s2, 32); s3 += __shfl_xor(s3, 32);
    m0 = fmaxf(m0, __shfl_xor(m0, 32)); m1 = fmaxf(m1, __shfl_xor(m1, 32));
    m2 = fmaxf(m2, __shfl_xor(m2, 32)); m3 = fmaxf(m3, __shfl_xor(m3, 32));
    int d = e - s;
    float inv = 1.f / fmaxf((float)d, 1.f);
    if(d == 0){ m0=0.f; m1=0.f; m2=0.f; m3=0.f; }
    if(half == 0){
        float4 xv = *reinterpret_cast<const float4*>(x + (size_t)node*NODE_IN + fi);
        size_t r = (size_t)node * IN_DIM;
        ushort4 u;
        u.x=f2bf(s0); u.y=f2bf(s1); u.z=f2bf(s2); u.w=f2bf(s3);
        *reinterpret_cast<ushort4*>(h0 + r + fi) = u;
        u.x=f2bf(m0); u.y=f2bf(m1); u.z=f2bf(m2); u.w=f2bf(m3);
        *reinterpret_cast<ushort4*>(h0 + r + 128 + fi) = u;
        u.x=f2bf(s0*inv); u.y=f2bf(s1*inv); u.z=f2bf(s2*inv); u.w=f2bf(s3*inv);
        *reinterpret_cast<ushort4*>(h0 + r + 256 + fi) = u;
        u.x=f2bf(xv.x); u.y=f2bf(xv.y); u.z=f2bf(xv.z); u.w=f2bf(xv.w);
        *reinterpret_cast<ushort4*>(h0 + r + 384 + fi) = u;
    }
}

// ---------- fused MLP v5: ROLLED kt-loops (small code), tiled staging, dbuf wt ----------
template<int NT>
static __device__ __forceinline__ void stage_w(const unsigned short* __restrict__ Wtil, int kt,
                                               unsigned short* dst, int w, int l){
    constexpr int TPW = NT/4;
    #pragma unroll
    for(int i=0;i<TPW;i++){
        int t = w*TPW + i;
        const unsigned short* src = Wtil + ((size_t)(kt*NT + t))*512 + l*8;
        __builtin_amdgcn_global_load_lds(
            (const __attribute__((address_space(1))) void*)src,
            (__attribute__((address_space(3))) void*)(dst + (size_t)t*512),
            16, 0, 0);
    }
}

template<int NT>
static __device__ __forceinline__ void ln_silu_store(
    f32x4* acc, const float* __restrict__ bias,
    const float* __restrict__ g, const float* __restrict__ be,
    __bf16* __restrict__ hrow, int l)
{
    int lr = l & 15, lg = l >> 4;
    float s[4] = {0,0,0,0}, q[4] = {0,0,0,0};
    #pragma unroll
    for(int t=0;t<NT;t++){
        float b = bias[t*16 + lr];
        #pragma unroll
        for(int j=0;j<4;j++){
            float z = acc[t][j] + b;
            acc[t][j] = z;
            s[j] += z; q[j] += z*z;
        }
    }
    #pragma unroll
    for(int m=1;m<16;m<<=1){
        #pragma unroll
        for(int j=0;j<4;j++){
            s[j] += __shfl_xor(s[j], m, 64);
            q[j] += __shfl_xor(q[j], m, 64);
        }
    }
    float mean[4], inv[4];
    #pragma unroll
    for(int j=0;j<4;j++){
        mean[j] = s[j] * (1.f/256.f);
        float var = q[j] * (1.f/256.f) - mean[j]*mean[j];
        inv[j] = rsqrtf(var + EPSLN);
    }
    #pragma unroll
    for(int t=0;t<NT;t++){
        int colb = t*16 + lr;
        float gg = g[colb], bb = be[colb];
        #pragma unroll
        for(int j=0;j<4;j++){
            int row = lg*4 + j;
            float y = (acc[t][j] - mean[j]) * inv[j] * gg + bb;
            float sil = y / (1.f + __expf(-y));
            int chunk = (colb >> 3) ^ (row & 7);
            hrow[row*256 + chunk*8 + (colb & 7)] = (__bf16)sil;
        }
    }
}

__global__ __launch_bounds__(256, 2) void k_mlp(
    const unsigned short* __restrict__ h0,
    const unsigned short* __restrict__ W0t, const float* __restrict__ b0, const float* __restrict__ g0, const float* __restrict__ be0,
    const unsigned short* __restrict__ W1t, const float* __restrict__ b1, const float* __restrict__ g1, const float* __restrict__ be1,
    const unsigned short* __restrict__ W2t, const float* __restrict__ b2, const float* __restrict__ g2, const float* __restrict__ be2,
    const unsigned short* __restrict__ W3t, const float* __restrict__ b3,
    float* __restrict__ out, int n)
{
    __shared__ __bf16 hb[4][16][256];            // 32 KB
    __shared__ unsigned short wt[2][16*512];     // 32 KB, double-buffered weight tile
    int w = threadIdx.x >> 6;
    int l = threadIdx.x & 63;
    int lr = l & 15, lg = l >> 4;
    int row0 = blockIdx.x*64 + w*16;
    __bf16* hrow = &hb[w][0][0];

    f32x4 acc[16];
    f32x4 zero = {0.f,0.f,0.f,0.f};

    // ---- L0: [16 x 512] @ [512 x 256]; A via 2-deep register pipeline (rolled) ----
    #pragma unroll
    for(int t=0;t<16;t++) acc[t] = zero;
    const unsigned short* ap = h0 + (size_t)(row0 + lr)*IN_DIM + lg*8;
    stage_w<16>(W0t, 0, wt[0], w, l);
    bfv8 a_cur = *reinterpret_cast<const bfv8*>(ap);
    __syncthreads();
    #pragma unroll 1
    for(int kt=0; kt<16; kt++){
        bfv8 a_nxt = a_cur;
        if(kt < 15){
            stage_w<16>(W0t, kt+1, wt[(kt+1)&1], w, l);
            a_nxt = *reinterpret_cast<const bfv8*>(ap + (kt+1)*32);
        }
        const unsigned short* wb = wt[kt&1] + l*8;
        #pragma unroll
        for(int t=0;t<16;t++){
            bfv8 b = *reinterpret_cast<const bfv8*>(wb + t*512);
            acc[t] = mfma16(a_cur, b, acc[t]);
        }
        a_cur = a_nxt;
        __syncthreads();
    }
    ln_silu_store<16>(acc, b0, g0, be0, hrow, l);

    // ---- L1 & L2 share one rolled loop body ----
    #pragma unroll 1
    for(int li=0; li<2; li++){
        const unsigned short* Wt = li ? W2t : W1t;
        const float* bi  = li ? b2  : b1;
        const float* gi  = li ? g2  : g1;
        const float* bei = li ? be2 : be1;
        #pragma unroll
        for(int t=0;t<16;t++) acc[t] = zero;
        stage_w<16>(Wt, 0, wt[0], w, l);
        __syncthreads();
        #pragma unroll 1
        for(int kt=0; kt<8; kt++){
            if(kt < 7) stage_w<16>(Wt, kt+1, wt[(kt+1)&1], w, l);
            int chunk = (kt*4 + lg) ^ (lr & 7);
            bfv8 av = *reinterpret_cast<const bfv8*>(hrow + lr*256 + chunk*8);
            const unsigned short* wb = wt[kt&1] + l*8;
            #pragma unroll
            for(int t=0;t<16;t++){
                bfv8 b = *reinterpret_cast<const bfv8*>(wb + t*512);
                acc[t] = mfma16(av, b, acc[t]);
            }
            __syncthreads();
        }
        ln_silu_store<16>(acc, bi, gi, bei, hrow, l);
    }

    // ---- L3: [16 x 256] @ [256 x 128] (rolled) ----
    #pragma unroll
    for(int t=0;t<8;t++) acc[t] = zero;
    stage_w<8>(W3t, 0, wt[0], w, l);
    __syncthreads();
    #pragma unroll 1
    for(int kt=0; kt<8; kt++){
        if(kt < 7) stage_w<8>(W3t, kt+1, wt[(kt+1)&1], w, l);
        int chunk = (kt*4 + lg) ^ (lr & 7);
        bfv8 av = *reinterpret_cast<const bfv8*>(hrow + lr*256 + chunk*8);
        const unsigned short* wb = wt[kt&1] + l*8;
        #pragma unroll
        for(int t=0;t<8;t++){
            bfv8 b = *reinterpret_cast<const bfv8*>(wb + t*512);
            acc[t] = mfma16(av, b, acc[t]);
        }
        __syncthreads();
    }
    #pragma unroll
    for(int t=0;t<8;t++){
        int col = t*16 + lr;
        float bb = b3[col];
        #pragma unroll
        for(int j=0;j<4;j++){
            int grow = row0 + lg*4 + j;
            if(grow < n) out[(size_t)grow*OUT_D + col] = acc[t][j] + bb;
        }
    }
}

extern "C" void kernel_launch(void* const* d_in, const int* in_sizes, int n_in,
                              void* d_out, int out_size, void* d_ws, size_t ws_size,
                              hipStream_t stream)
{
    const float* x          = (const float*)d_in[0];
    const int*   edge_index = (const int*)d_in[1];
    const float* edge_attr  = (const float*)d_in[2];
    const float* W0  = (const float*)d_in[5];
    const float* b0  = (const float*)d_in[6];
    const float* g0  = (const float*)d_in[7];
    const float* be0 = (const float*)d_in[8];
    const float* W1  = (const float*)d_in[9];
    const float* b1  = (const float*)d_in[10];
    const float* g1  = (const float*)d_in[11];
    const float* be1 = (const float*)d_in[12];
    const float* W2  = (const float*)d_in[13];
    const float* b2  = (const float*)d_in[14];
    const float* g2  = (const float*)d_in[15];
    const float* be2 = (const float*)d_in[16];
    const float* W3  = (const float*)d_in[17];
    const float* b3  = (const float*)d_in[18];

    int N = in_sizes[0] / NODE_IN;
    int E = in_sizes[2] / EDGE_INF;
    const int* col = edge_index + E;   // edge_index[1]

    char* p = (char*)d_ws;
    auto alloc = [&](size_t bytes) -> char* {
        char* r = p; p += (bytes + 255) & ~(size_t)255; return r;
    };
    int* deg     = (int*)alloc((size_t)N*4);
    int* indptr  = (int*)alloc((size_t)(N+1)*4);
    int* cursor  = (int*)alloc((size_t)N*4);
    int* edge_of = (int*)alloc((size_t)E*4);
    int nb = (N + 1023) / 1024;
    int* bsum    = (int*)alloc((size_t)nb*4);
    int Mpad = ((N + 63)/64)*64;
    unsigned short* h0  = (unsigned short*)alloc((size_t)Mpad*IN_DIM*2);
    unsigned short* W0t = (unsigned short*)alloc((size_t)IN_DIM*HIDW*2);
    unsigned short* W1t = (unsigned short*)alloc((size_t)HIDW*HIDW*2);
    unsigned short* W2t = (unsigned short*)alloc((size_t)HIDW*HIDW*2);
    unsigned short* W3t = (unsigned short*)alloc((size_t)HIDW*OUT_D*2);

    hipMemsetAsync(deg, 0, (size_t)N*4, stream);

    k_wconv_all<<<(294912+255)/256, 256, 0, stream>>>(W0, W1, W2, W3, W0t, W1t, W2t, W3t);

    k_count<<<(E+255)/256, 256, 0, stream>>>(col, deg, E);
    k_scan1<<<nb, 256, 0, stream>>>(deg, bsum, N);
    k_scan2<<<1, 128, 0, stream>>>(bsum, nb);
    k_scan3<<<nb, 256, 0, stream>>>(deg, bsum, indptr, cursor, N);
    k_scatter<<<(E+255)/256, 256, 0, stream>>>(col, cursor, edge_of, E);
    k_gather<<<(N+3)/4, 256, 0, stream>>>(indptr, edge_of, edge_attr, x, h0, N);

    k_mlp<<<Mpad/64, 256, 0, stream>>>(h0,
        W0t, b0, g0, be0, W1t, b1, g1, be1, W2t, b2, g2, be2, W3t, b3,
        (float*)d_out, N);
}